// Round 8
// baseline (295.919 us; speedup 1.0000x reference)
//
#include <hip/hip_runtime.h>

#define NB 8
#define NT 2048
#define NC 2048
#define NH 128

typedef short s8v __attribute__((ext_vector_type(8)));   // 8 bf16 (4 VGPRs) — MFMA A/B frag
typedef short s4v __attribute__((ext_vector_type(4)));   // 4 bf16 (8 B)
typedef float f4  __attribute__((ext_vector_type(4)));   // 4 fp32 — MFMA C/D frag

static __device__ __forceinline__ unsigned short f2bf(float f) {
    union { float f; unsigned int u; } v; v.f = f;
    unsigned int x = v.u;
    return (unsigned short)((x + 0x7FFFu + ((x >> 16) & 1u)) >> 16);  // RNE
}

static __device__ __forceinline__ s8v pack8(f4 lo, f4 hi) {          // fp32x8 -> bf16x8 (trunc)
    union { f4 f; unsigned int u[4]; } L, H; L.f = lo; H.f = hi;
    union { s8v s; unsigned int u[4]; } A;
    A.u[0] = __builtin_amdgcn_perm(L.u[1], L.u[0], 0x07060302u);
    A.u[1] = __builtin_amdgcn_perm(L.u[3], L.u[2], 0x07060302u);
    A.u[2] = __builtin_amdgcn_perm(H.u[1], H.u[0], 0x07060302u);
    A.u[3] = __builtin_amdgcn_perm(H.u[3], H.u[2], 0x07060302u);
    return A.s;
}

// async global->LDS, 16B/lane; LDS dest = wave-uniform base + lane*16 (HW adds lane term)
static __device__ __forceinline__ void gl2lds16(const void* g, void* lds_base) {
    __builtin_amdgcn_global_load_lds(
        (const __attribute__((address_space(1))) unsigned int*)g,
        (__attribute__((address_space(3))) unsigned int*)lds_base, 16, 0, 0);
}

// ---------------------------------------------------------------------------
// Kernel 0: transpose + cast W[k][n] (2048x128 fp32) -> FRAGMENT-PACKED bf16:
// wt[nb][kb][quad*16+l16][8elems]  (nb = mat*8 + n/16, kb = k/32).
// grid (32 k-tiles of 64, 3 mats), block 256.  [verified R3-R7]
// ---------------------------------------------------------------------------
__global__ __launch_bounds__(256) void wtrans_k(
    const float* __restrict__ Wk, const float* __restrict__ Wq,
    const float* __restrict__ Wv, unsigned short* __restrict__ wt)
{
    __shared__ float Ls[64][129];                       // +1 pad: conflict-free transpose
    const int mat = blockIdx.y;
    const float* W = (mat == 0) ? Wq : (mat == 1) ? Wk : Wv;
    const int k0 = blockIdx.x * 64;
    const int t  = threadIdx.x;

    #pragma unroll
    for (int j = 0; j < 8; ++j) {                       // load 64x128 fp32, coalesced f4
        int flat = j * 1024 + t * 4;
        int k = flat >> 7, n = flat & 127;
        f4 v = *reinterpret_cast<const f4*>(W + (size_t)(k0 + k) * NH + n);
        Ls[k][n] = v[0]; Ls[k][n + 1] = v[1]; Ls[k][n + 2] = v[2]; Ls[k][n + 3] = v[3];
    }
    __syncthreads();

    const int n = t >> 1, half = t & 1;                 // thread: col n, one 32-k block
    unsigned short tmp[32];
    #pragma unroll
    for (int kk = 0; kk < 32; ++kk) tmp[kk] = f2bf(Ls[half * 32 + kk][n]);

    const int nb  = mat * 8 + (n >> 4);                 // 0..23
    const int l16 = n & 15;
    const int kbi = blockIdx.x * 2 + half;              // 0..63
    unsigned short* dst = wt + ((size_t)nb * 64 + kbi) * 512;
    #pragma unroll
    for (int v = 0; v < 4; ++v)                         // lane (l16, quad=v) slot
        *reinterpret_cast<s8v*>(dst + (v * 16 + l16) * 8) = *reinterpret_cast<s8v*>(tmp + v * 8);
}

// ---------------------------------------------------------------------------
// Kernel 1: FUSED projection (Q,K,V in one pass over x) + RoPE.
// R8: tests the B-L2-bandwidth hypothesis (R5/R6/R7 all ~92 µs at constant
// 768 MB B traffic). M-tile 64, grid 256, block 512 (8 waves, 1m x 8n,
// acc[4][3]) -> B traffic HALVED to 384 MB (no m-duplication, half blocks).
// x staged via global_load_lds (R1's structure: measured 0 bank conflicts,
// 3.8 TB/s effective) with T3-correct ordering per iter:
//   [B loads tile t] -> [gl2lds stage tile t+1] -> [ds_read+pack+24 MFMA]
//   -> barrier (single vmcnt(0) drain per tile, stage latency hidden under
//   compute; B's MFMA wait is vmcnt(2), not a full drain, since B issued
//   BEFORE the stage). XOR chunk swizzle on the global source (pos =
//   chunk ^ (row&15)), same XOR on LDS read -> conflict-free b128.
// No VGPR-capping launch bounds (R6 spill lesson).
// Outputs MFMA-FRAGMENT-PACKED for attn_k (mapping verified R5/R7).
// ---------------------------------------------------------------------------
__global__ __launch_bounds__(512) void proj_rope(
    const float* __restrict__ x, const unsigned short* __restrict__ wt,
    unsigned short* __restrict__ qp, unsigned short* __restrict__ kp,
    unsigned short* __restrict__ vp)
{
    __shared__ float Xs[2][4096];                        // 2 x 16KB fp32 (64 rows x 64 k)

    const int tid  = threadIdx.x;
    const int wave = tid >> 6;                           // = n-wave (0..7)
    const int lane = tid & 63;
    const int quad = lane >> 4, l16 = lane & 15;
    const int M0 = blockIdx.x * 64;

    // gl2lds staging: 2 slots/wave, slot s covers rows wave*8+s*4+(lane>>4);
    // global col chunk pre-swizzled so LDS holds chunk c at pos c^(row&15)
    const float* xsrc[2];
    #pragma unroll
    for (int s = 0; s < 2; ++s) {
        const int xrow = wave * 8 + s * 4 + (lane >> 4);
        const int xcol = ((lane & 15) ^ (xrow & 15)) * 4;
        xsrc[s] = x + (size_t)(M0 + xrow) * NC + xcol;
    }

    const unsigned short* wtb = wt + (size_t)(wave * 3) * 32768 + lane * 8;

    f4 acc[4][3];
    #pragma unroll
    for (int mi = 0; mi < 4; ++mi)
        #pragma unroll
        for (int ni = 0; ni < 3; ++ni)
            acc[mi][ni] = (f4){0.f, 0.f, 0.f, 0.f};

    // prologue: stage tile 0 -> buf0
    #pragma unroll
    for (int s = 0; s < 2; ++s)
        gl2lds16(xsrc[s], (char*)Xs[0] + (wave * 2 + s) * 1024);
    __syncthreads();

    for (int t = 0; t < 32; ++t) {
        // B fragments for tile t FIRST (so MFMA's vmcnt wait excludes the stage)
        s8v b[2][3];
        #pragma unroll
        for (int ks = 0; ks < 2; ++ks)
            #pragma unroll
            for (int ni = 0; ni < 3; ++ni)
                b[ks][ni] = *reinterpret_cast<const s8v*>(
                    wtb + (size_t)ni * 32768 + (size_t)(t * 2 + ks) * 512);
        if (t < 31) {                                    // stage tile t+1 -> other buf
            #pragma unroll
            for (int s = 0; s < 2; ++s)
                gl2lds16(xsrc[s] + (t + 1) * 64, (char*)Xs[(t + 1) & 1] + (wave * 2 + s) * 1024);
        }
        const float* cur = Xs[t & 1];
        #pragma unroll
        for (int ksub = 0; ksub < 2; ++ksub) {
            s8v a[4];
            #pragma unroll
            for (int mi = 0; mi < 4; ++mi) {
                const int rb = (mi * 16 + l16) * 64;              // row base (floats)
                const int p0 = (ksub * 8 + quad * 2) ^ l16;       // even chunk
                f4 L = *reinterpret_cast<const f4*>(cur + rb + p0 * 4);
                f4 H = *reinterpret_cast<const f4*>(cur + rb + (p0 ^ 1) * 4);
                a[mi] = pack8(L, H);
            }
            #pragma unroll
            for (int ni = 0; ni < 3; ++ni)
                #pragma unroll
                for (int mi = 0; mi < 4; ++mi)
                    acc[mi][ni] = __builtin_amdgcn_mfma_f32_16x16x32_bf16(a[mi], b[ksub][ni], acc[mi][ni], 0, 0, 0);
        }
        __syncthreads();   // drains stage t+1; all waves done reading buf[t&1]
    }

    // ---- epilogue: RoPE + fragment-packed stores (R5/R7 mapping, M=64) ----
    const float cfreq = -0.10381025296f;  // -log2(10000)/128
    const int tb = M0 >> 11;              // batch
    const int tl = M0 & 2047;             // t of first row (multiple of 64)
    unsigned short* qpB = qp + (size_t)tb * 262144;
    unsigned short* kpB = kp + (size_t)tb * 262144;
    unsigned short* vpB = vp + (size_t)tb * 262144;
    const int kt0 = tl >> 6;              // k/v tile (64 rows)

    #pragma unroll
    for (int mi = 0; mi < 4; ++mi) {
        #pragma unroll
        for (int ni = 0; ni < 3; ++ni) {
            const int outcol = wave * 48 + ni * 16 + l16;   // 0..383
            const int mat = outcol >> 7;                    // uniform per (wave,ni)
            const int col = outcol & 127;
            float vv[4];
            #pragma unroll
            for (int r = 0; r < 4; ++r) {
                const int t = tl + mi * 16 + quad * 4 + r;
                float v = acc[mi][ni][r];
                if (mat < 2) {
                    float other = __shfl_xor(v, 1, 64);
                    float freq  = exp2f(cfreq * (float)(col & ~1));
                    float ang   = (float)t * freq;
                    float sn = sinf(ang), cs = cosf(ang);
                    v = (col & 1) ? (other * sn + v * cs)
                                  : (v * cs - other * sn);
                }
                vv[r] = v;
            }
            if (mat == 0) {
                const int qt = (tl >> 5) + (mi >> 1);       // 32-row q-tile
                const int ks = col >> 5, qq = (col >> 3) & 3, e = col & 7;
                unsigned short* d = qpB + ((((size_t)qt * 2 + (mi & 1)) * 4 + ks) * 64 + qq * 16 + quad * 4) * 8 + e;
                #pragma unroll
                for (int r = 0; r < 4; ++r) d[r * 8] = f2bf(vv[r]);
            } else if (mat == 1) {
                const int ks = col >> 5, qq = (col >> 3) & 3, e = col & 7;
                unsigned short* d = kpB + ((((size_t)kt0 * 4 + mi) * 4 + ks) * 64 + qq * 16 + quad * 4) * 8 + e;
                #pragma unroll
                for (int r = 0; r < 4; ++r) d[r * 8] = f2bf(vv[r]);
            } else {
                const int dt  = col >> 4;                    // l16v == l16
                const int ks2 = mi >> 1;
                const int qv  = (mi & 1) * 2 + (quad >> 1);
                const int e4  = (quad & 1) * 4;
                unsigned short* d = vpB + ((((size_t)kt0 * 2 + ks2) * 8 + dt) * 64 + qv * 16 + l16) * 8 + e4;
                s4v pk;
                #pragma unroll
                for (int r = 0; r < 4; ++r) pk[r] = (short)f2bf(vv[r]);
                *reinterpret_cast<s4v*>(d) = pk;
            }
        }
    }
}

// ---------------------------------------------------------------------------
// Kernel 2: flash attention (causal). 32 q-rows per wave (2 m-frags),
// split-KV stride 4 across the block's 4 waves, private online-softmax state,
// LDS merge at the end. grid = (64 q-tiles of 32, 8 batches), block 256.
// EXACT R5/R7 version. Q/K/V FRAGMENT-PACKED: all loads 1KB coalesced bursts.
// Softmax in log2 domain + T13 defer-max (THR=8). P XOR-swizzled.
// ---------------------------------------------------------------------------
__global__ __launch_bounds__(256, 2) void attn_k(
    const unsigned short* __restrict__ qp, const unsigned short* __restrict__ kp,
    const unsigned short* __restrict__ vp, float* __restrict__ out)
{
    __shared__ unsigned short P[4][32 * 64];   // 16 KB, per-wave, swizzled
    __shared__ float Os[4][32][64];            // 32 KB (one half of d per pass)
    __shared__ float Ms[4][32], Ls[4][32], Lt[32];

    const int wave = threadIdx.x >> 6;
    const int lane = threadIdx.x & 63;
    const int quad = lane >> 4, l16 = lane & 15;
    const int b     = blockIdx.y;
    const int qrow0 = blockIdx.x * 32;
    const int qt    = blockIdx.x;
    const unsigned short* Qp = qp + (size_t)b * 262144;
    const unsigned short* Kp = kp + (size_t)b * 262144;
    const unsigned short* Vp = vp + (size_t)b * 262144;

    s8v qf[2][4];
    #pragma unroll
    for (int mi = 0; mi < 2; ++mi)
        #pragma unroll
        for (int ks = 0; ks < 4; ++ks)
            qf[mi][ks] = *reinterpret_cast<const s8v*>(
                Qp + ((((size_t)qt * 2 + mi) * 4 + ks) * 64 + lane) * 8);

    float m[2][4], ls[2][4];
    f4 o[2][8];
    #pragma unroll
    for (int mi = 0; mi < 2; ++mi) {
        #pragma unroll
        for (int r = 0; r < 4; ++r) { m[mi][r] = -INFINITY; ls[mi][r] = 0.f; }
        #pragma unroll
        for (int dt = 0; dt < 8; ++dt) o[mi][dt] = (f4){0.f, 0.f, 0.f, 0.f};
    }

    const int nkt = (qrow0 >> 6) + 1;        // works for qrow0 = 0/32 mod 64
    const float scale2 = 0.1275166948f;      // (1/sqrt(128)) * log2(e)

    for (int kt = wave; kt < nkt; kt += 4) {
        const int kbase = kt * 64;
        const bool domask = (kt == nkt - 1);
        const unsigned short* Kt = Kp + (size_t)kt * 8192;   // [nt][ks][lane][8]
        const unsigned short* Vt = Vp + (size_t)kt * 8192;   // [ks2][dt][lane][8]

        // S = Q K^T
        f4 s[2][4];
        #pragma unroll
        for (int nt = 0; nt < 4; ++nt) {
            f4 a0 = (f4){0.f, 0.f, 0.f, 0.f}, a1 = a0;
            #pragma unroll
            for (int ks = 0; ks < 4; ++ks) {
                s8v kf = *reinterpret_cast<const s8v*>(Kt + (((nt * 4 + ks) * 64) + lane) * 8);
                a0 = __builtin_amdgcn_mfma_f32_16x16x32_bf16(qf[0][ks], kf, a0, 0, 0, 0);
                a1 = __builtin_amdgcn_mfma_f32_16x16x32_bf16(qf[1][ks], kf, a1, 0, 0, 0);
            }
            s[0][nt] = a0; s[1][nt] = a1;
        }

        // tile max (log2 domain)
        float tmx[2][4];
        #pragma unroll
        for (int mi = 0; mi < 2; ++mi) {
            #pragma unroll
            for (int r = 0; r < 4; ++r) {
                const int trow = qrow0 + mi * 16 + quad * 4 + r;
                #pragma unroll
                for (int nt = 0; nt < 4; ++nt) {
                    float sv = s[mi][nt][r] * scale2;
                    if (domask && (kbase + nt * 16 + l16 > trow)) sv = -INFINITY;
                    s[mi][nt][r] = sv;
                }
                float tm = fmaxf(fmaxf(s[mi][0][r], s[mi][1][r]),
                                 fmaxf(s[mi][2][r], s[mi][3][r]));
                #pragma unroll
                for (int off = 1; off < 16; off <<= 1)
                    tm = fmaxf(tm, __shfl_xor(tm, off, 64));
                tmx[mi][r] = tm;
            }
        }

        // defer-max: only rescale when some row's max grew by > 8 (log2 units)
        bool grow = false;
        #pragma unroll
        for (int mi = 0; mi < 2; ++mi)
            #pragma unroll
            for (int r = 0; r < 4; ++r)
                grow = grow || (tmx[mi][r] > m[mi][r] + 8.0f);
        if (__any(grow)) {
            #pragma unroll
            for (int mi = 0; mi < 2; ++mi)
                #pragma unroll
                for (int r = 0; r < 4; ++r) {
                    const float mn = fmaxf(m[mi][r], tmx[mi][r]);
                    const float alpha = exp2f(m[mi][r] - mn);
                    m[mi][r] = mn;
                    ls[mi][r] *= alpha;
                    #pragma unroll
                    for (int dt = 0; dt < 8; ++dt) o[mi][dt][r] *= alpha;
                }
        }

        // P = exp2(S - m); per-lane partial row sums
        #pragma unroll
        for (int mi = 0; mi < 2; ++mi)
            #pragma unroll
            for (int r = 0; r < 4; ++r) {
                float rs = 0.f;
                #pragma unroll
                for (int nt = 0; nt < 4; ++nt) {
                    float p = exp2f(s[mi][nt][r] - m[mi][r]);
                    s[mi][nt][r] = p;
                    rs += p;
                }
                ls[mi][r] += rs;
            }

        // P (C layout) -> LDS, XOR-swizzled: pos = chunk ^ (row&7), chunk=8 shorts
        #pragma unroll
        for (int mi = 0; mi < 2; ++mi)
            #pragma unroll
            for (int nt = 0; nt < 4; ++nt)
                #pragma unroll
                for (int r = 0; r < 4; ++r) {
                    const int prow = mi * 16 + quad * 4 + r;
                    const int swz  = ((nt * 2 + (l16 >> 3)) ^ (prow & 7)) * 8 + (l16 & 7);
                    P[wave][prow * 64 + swz] = f2bf(s[mi][nt][r]);
                }

        // O += P @ V
        #pragma unroll
        for (int ks2 = 0; ks2 < 2; ++ks2) {
            s8v pa[2];
            #pragma unroll
            for (int mi = 0; mi < 2; ++mi) {
                const int prow = mi * 16 + l16;                  // prow&7 == l16&7
                const int pp = ((ks2 * 4 + quad) ^ (l16 & 7));
                pa[mi] = *reinterpret_cast<const s8v*>(&P[wave][prow * 64 + pp * 8]);
            }
            #pragma unroll
            for (int dt = 0; dt < 8; ++dt) {
                s8v vf = *reinterpret_cast<const s8v*>(Vt + (((ks2 * 8 + dt) * 64) + lane) * 8);
                o[0][dt] = __builtin_amdgcn_mfma_f32_16x16x32_bf16(pa[0], vf, o[0][dt], 0, 0, 0);
                o[1][dt] = __builtin_amdgcn_mfma_f32_16x16x32_bf16(pa[1], vf, o[1][dt], 0, 0, 0);
            }
        }
    }

    // reduce per-lane lsum across the 16-lane row group
    #pragma unroll
    for (int mi = 0; mi < 2; ++mi)
        #pragma unroll
        for (int r = 0; r < 4; ++r) {
            float v = ls[mi][r];
            #pragma unroll
            for (int off = 1; off < 16; off <<= 1) v += __shfl_xor(v, off, 64);
            ls[mi][r] = v;
        }

    // ---- merge the 4 per-wave partials (m in log2 domain -> exp2) ----
    if (l16 == 0) {
        #pragma unroll
        for (int mi = 0; mi < 2; ++mi)
            #pragma unroll
            for (int r = 0; r < 4; ++r) {
                Ms[wave][mi * 16 + quad * 4 + r] = m[mi][r];
                Ls[wave][mi * 16 + quad * 4 + r] = ls[mi][r];
            }
    }
    __syncthreads();

    #pragma unroll
    for (int mi = 0; mi < 2; ++mi)
        #pragma unroll
        for (int r = 0; r < 4; ++r) {
            const int row = mi * 16 + quad * 4 + r;
            float M = fmaxf(fmaxf(Ms[0][row], Ms[1][row]), fmaxf(Ms[2][row], Ms[3][row]));
            float sc = exp2f(m[mi][r] - M);
            float lt = Ls[0][row] * exp2f(Ms[0][row] - M) + Ls[1][row] * exp2f(Ms[1][row] - M)
                     + Ls[2][row] * exp2f(Ms[2][row] - M) + Ls[3][row] * exp2f(Ms[3][row] - M);
            if (wave == 0 && l16 == 0) Lt[row] = lt;
            #pragma unroll
            for (int dt = 0; dt < 8; ++dt) o[mi][dt][r] *= sc;
        }

    const int rrow = threadIdx.x >> 3;          // 0..31
    const int cx   = (threadIdx.x & 7) * 8;     // 0..56
    #pragma unroll
    for (int h = 0; h < 2; ++h) {
        __syncthreads();
        #pragma unroll
        for (int mi = 0; mi < 2; ++mi)
            #pragma unroll
            for (int dtl = 0; dtl < 4; ++dtl)
                #pragma unroll
                for (int r = 0; r < 4; ++r)
                    Os[wave][mi * 16 + quad * 4 + r][dtl * 16 + l16] = o[mi][h * 4 + dtl][r];
        __syncthreads();
        f4 s0 = (f4){0.f, 0.f, 0.f, 0.f}, s1 = s0;
        #pragma unroll
        for (int w = 0; w < 4; ++w) {
            s0 += *reinterpret_cast<const f4*>(&Os[w][rrow][cx]);
            s1 += *reinterpret_cast<const f4*>(&Os[w][rrow][cx + 4]);
        }
        const float rl = 1.0f / Lt[rrow];
        float* dst = &out[((size_t)b * NT + qrow0 + rrow) * NH + h * 64 + cx];
        *reinterpret_cast<f4*>(dst)     = s0 * rl;
        *reinterpret_cast<f4*>(dst + 4) = s1 * rl;
    }
}

// ---------------------------------------------------------------------------
extern "C" void kernel_launch(void* const* d_in, const int* in_sizes, int n_in,
                              void* d_out, int out_size, void* d_ws, size_t ws_size,
                              hipStream_t stream) {
    const float* x  = (const float*)d_in[0];
    const float* Wk = (const float*)d_in[1];
    const float* Wq = (const float*)d_in[2];
    const float* Wv = (const float*)d_in[3];
    unsigned short* ws   = (unsigned short*)d_ws;
    unsigned short* wt   = ws;                      // 24 nb x 64 kb x 512 (packed W frags)
    unsigned short* qws  = ws  + 786432;            // 8 b x 64 qt x 2 x 4 x 64 x 8 (packed Q)
    unsigned short* kws  = qws + 2097152;           // 8 b x 32 kt x 4 x 4 x 64 x 8 (packed K)
    unsigned short* vtws = kws + 2097152;           // 8 b x 32 kt x 2 x 8 x 64 x 8 (packed V^T)
    float* outp = (float*)d_out;

    wtrans_k<<<dim3(32, 3), 256, 0, stream>>>(Wk, Wq, Wv, wt);
    proj_rope<<<dim3(256), 512, 0, stream>>>(x, wt, qws, kws, vtws);
    attn_k<<<dim3(64, 8), 256, 0, stream>>>(qws, kws, vtws, outp);
}